// Round 3
// baseline (404.202 us; speedup 1.0000x reference)
//
#include <hip/hip_runtime.h>
#include <math.h>

// Shapes (fixed by the reference)
#define BB   16
#define CC   16      // IN_CHAN
#define LL   4096
#define OUTC 64
#define KS   7

typedef float vfloat4 __attribute__((ext_vector_type(4)));

// ---------------------------------------------------------------------------
// Pre-pass: transpose x (B,L,C) -> xT (B,C,L) so bilinear gathers are
// contiguous along l (the gather axis).
// ---------------------------------------------------------------------------
__global__ __launch_bounds__(256) void transpose_kernel(
    const float* __restrict__ x, float* __restrict__ xT)
{
    __shared__ float tile[64 * 17];  // 64 l x 16 c, stride 17 (conflict-free)
    const int b   = blockIdx.x >> 6;
    const int l0  = (blockIdx.x & 63) * 64;
    const int tid = threadIdx.x;
    {
        const int lo = tid >> 2, cq = (tid & 3) * 4;
        float4 v = *(const float4*)(x + ((size_t)(b * LL + l0 + lo)) * CC + cq);
        tile[lo * 17 + cq + 0] = v.x;
        tile[lo * 17 + cq + 1] = v.y;
        tile[lo * 17 + cq + 2] = v.z;
        tile[lo * 17 + cq + 3] = v.w;
    }
    __syncthreads();
    {
        const int c = tid >> 4, li = (tid & 15) * 4;
        float4 v;
        v.x = tile[(li + 0) * 17 + c];
        v.y = tile[(li + 1) * 17 + c];
        v.z = tile[(li + 2) * 17 + c];
        v.w = tile[(li + 3) * 17 + c];
        *(float4*)(xT + ((size_t)(b * CC + c)) * LL + l0 + li) = v;
    }
}

// ---------------------------------------------------------------------------
// Main kernel: identical to Round-2 version (unchanged for calibration).
// NO LDS, NO barrier; weights via wave-uniform s_loads.
// Thread = (l, channel-quad): tid>>2 = l offset (32), tid&3 = c-quad (4).
// Block = 128 threads, grid = 16 b x 128 l-tiles = 2048 blocks.
// ---------------------------------------------------------------------------
template <bool USE_XT>
__global__ __launch_bounds__(128, 6) void deform_conv_kernel(
    const float* __restrict__ x,    // (B,1,L,C)
    const float* __restrict__ xT,   // (B,C,L) or nullptr
    const float* __restrict__ p_w, const float* __restrict__ p_b,
    const float* __restrict__ m_w, const float* __restrict__ m_b,
    const float* __restrict__ c_w, const float* __restrict__ c_b,
    float* __restrict__ out)        // (B,64,L,C)
{
    const int tid   = threadIdx.x;
    const int b     = blockIdx.x >> 7;   // 16 batches
    const int ltile = blockIdx.x & 127;  // 128 tiles of 32 positions
    const int l     = ltile * 32 + (tid >> 2);
    const int c0    = (tid & 3) * 4;     // channel quad

    const float* xb = x + (size_t)b * (LL * CC);

    // 3-tap conv inputs (zero pad at boundaries); coalesced float4 loads
    float s_m1[4] = {0.f, 0.f, 0.f, 0.f};
    float s_p1[4] = {0.f, 0.f, 0.f, 0.f};
    float s_0[4];
    {
        float4 v0 = *(const float4*)(xb + l * CC + c0);
        s_0[0] = v0.x; s_0[1] = v0.y; s_0[2] = v0.z; s_0[3] = v0.w;
        if (l > 0) {
            float4 vm = *(const float4*)(xb + (l - 1) * CC + c0);
            s_m1[0] = vm.x; s_m1[1] = vm.y; s_m1[2] = vm.z; s_m1[3] = vm.w;
        }
        if (l < LL - 1) {
            float4 vp = *(const float4*)(xb + (l + 1) * CC + c0);
            s_p1[0] = vp.x; s_p1[1] = vp.y; s_p1[2] = vp.z; s_p1[3] = vp.w;
        }
    }

    // x_off[c][k]: bilinear-gathered, masked samples.
    float xoff[4][KS];
    const float pl = (float)(l + 1);
    const float* xt0 = USE_XT ? (xT + (size_t)(b * CC + c0) * LL) : nullptr;
    #pragma unroll
    for (int k = 0; k < KS; ++k) {
        const float pw0 = p_w[k * 3 + 0], pw1 = p_w[k * 3 + 1],
                    pw2 = p_w[k * 3 + 2], pbk = p_b[k];
        const float mw0 = m_w[k * 3 + 0], mw1 = m_w[k * 3 + 1],
                    mw2 = m_w[k * 3 + 2], mbk = m_b[k];
        const float pn = (float)(k - 3);
        #pragma unroll
        for (int c = 0; c < 4; ++c) {
            float off  = pbk + pw0 * s_m1[c] + pw1 * s_0[c] + pw2 * s_p1[c];
            float mact = mbk + mw0 * s_m1[c] + mw1 * s_0[c] + mw2 * s_p1[c];
            float mm   = 1.f / (1.f + __expf(-mact));   // sigmoid

            float p    = pl + pn + off;
            float qltf = fminf(fmaxf(floorf(p), 0.f), (float)(LL - 1));
            float qrbf = fminf(qltf + 1.f, (float)(LL - 1));
            float pc   = fminf(fmaxf(p, 0.f), (float)(LL - 1));
            float glt  = 1.f + (qltf - pc);
            float grb  = 1.f - (qrbf - pc);

            float xlt, xrb;
            if (USE_XT) {
                // Contiguous along l: neighbors are adjacent floats.
                int iload = (int)fminf(qltf, (float)(LL - 2));
                const float* pr = xt0 + (size_t)c * LL + iload;
                float va = pr[0];
                float vb = pr[1];
                xlt = (qltf >= (float)(LL - 1)) ? vb : va;
                xrb = vb;
            } else {
                int ilt = (int)qltf;
                int irb = (int)qrbf;
                xlt = xb[ilt * CC + c0 + c];
                xrb = xb[irb * CC + c0 + c];
            }
            xoff[c][k] = (glt * xlt + grb * xrb) * mm;
        }
    }

    // 7 -> 64 output-channel dot. Weights via uniform (scalar) loads.
    float* outp = out + ((size_t)(b * OUTC) * LL + l) * CC + c0;
    #pragma unroll 4
    for (int o = 0; o < OUTC; ++o) {
        const float* cw = c_w + o * 7;   // uniform -> s_load
        const float w0 = cw[0], w1 = cw[1], w2 = cw[2], w3 = cw[3],
                    w4 = cw[4], w5 = cw[5], w6 = cw[6];
        const float bias = c_b[o];
        vfloat4 res;
        #pragma unroll
        for (int c = 0; c < 4; ++c) {
            float a = bias;
            a += w0 * xoff[c][0];
            a += w1 * xoff[c][1];
            a += w2 * xoff[c][2];
            a += w3 * xoff[c][3];
            a += w4 * xoff[c][4];
            a += w5 * xoff[c][5];
            a += w6 * xoff[c][6];
            res[c] = a;
        }
        *(vfloat4*)(outp + (size_t)o * (LL * CC)) = res;
    }
}

extern "C" void kernel_launch(void* const* d_in, const int* in_sizes, int n_in,
                              void* d_out, int out_size, void* d_ws, size_t ws_size,
                              hipStream_t stream) {
    const float* x   = (const float*)d_in[0];
    const float* p_w = (const float*)d_in[1];
    const float* p_b = (const float*)d_in[2];
    const float* m_w = (const float*)d_in[3];
    const float* m_b = (const float*)d_in[4];
    const float* c_w = (const float*)d_in[5];
    const float* c_b = (const float*)d_in[6];
    float* out = (float*)d_out;

    const size_t xt_bytes = (size_t)BB * CC * LL * sizeof(float);  // 4 MB
    if (d_ws != nullptr && ws_size >= xt_bytes) {
        float* xT = (float*)d_ws;
        transpose_kernel<<<dim3(BB * 64), dim3(256), 0, stream>>>(x, xT);
        // CALIBRATION: launch the main kernel 3x (idempotent, deterministic).
        // K_main = (dur_us[R3] - dur_us[R2]) / 2 -- measures the kernel's own
        // duration independent of the harness's poison-fill overhead.
        deform_conv_kernel<true><<<dim3(BB * 128), dim3(128), 0, stream>>>(
            x, xT, p_w, p_b, m_w, m_b, c_w, c_b, out);
        deform_conv_kernel<true><<<dim3(BB * 128), dim3(128), 0, stream>>>(
            x, xT, p_w, p_b, m_w, m_b, c_w, c_b, out);
        deform_conv_kernel<true><<<dim3(BB * 128), dim3(128), 0, stream>>>(
            x, xT, p_w, p_b, m_w, m_b, c_w, c_b, out);
    } else {
        deform_conv_kernel<false><<<dim3(BB * 128), dim3(128), 0, stream>>>(
            x, nullptr, p_w, p_b, m_w, m_b, c_w, c_b, out);
    }
}

// Round 4
// 282.955 us; speedup vs baseline: 1.4285x; 1.4285x over previous
//
#include <hip/hip_runtime.h>
#include <math.h>

// Shapes (fixed by the reference)
#define BB   16
#define CC   16      // IN_CHAN
#define LL   4096
#define OUTC 64
#define KS   7

typedef float vfloat4 __attribute__((ext_vector_type(4)));

// ---------------------------------------------------------------------------
// Pre-pass: transpose x (B,L,C) -> xT (B,C,L) so bilinear gathers are
// contiguous along l (the gather axis) and each (xlt,xrb) pair is one dwordx2.
// ---------------------------------------------------------------------------
__global__ __launch_bounds__(256) void transpose_kernel(
    const float* __restrict__ x, float* __restrict__ xT)
{
    __shared__ float tile[64 * 17];  // 64 l x 16 c, stride 17 (conflict-free)
    const int b   = blockIdx.x >> 6;
    const int l0  = (blockIdx.x & 63) * 64;
    const int tid = threadIdx.x;
    {
        const int lo = tid >> 2, cq = (tid & 3) * 4;
        float4 v = *(const float4*)(x + ((size_t)(b * LL + l0 + lo)) * CC + cq);
        tile[lo * 17 + cq + 0] = v.x;
        tile[lo * 17 + cq + 1] = v.y;
        tile[lo * 17 + cq + 2] = v.z;
        tile[lo * 17 + cq + 3] = v.w;
    }
    __syncthreads();
    {
        const int c = tid >> 4, li = (tid & 15) * 4;
        float4 v;
        v.x = tile[(li + 0) * 17 + c];
        v.y = tile[(li + 1) * 17 + c];
        v.z = tile[(li + 2) * 17 + c];
        v.w = tile[(li + 3) * 17 + c];
        *(float4*)(xT + ((size_t)(b * CC + c)) * LL + l0 + li) = v;
    }
}

// ---------------------------------------------------------------------------
// Main kernel. Geometry changed for BLOCK-LEVEL PIPELINING:
//   - 1 wave per block (64 thr = 16 l x 4 channel-quads); wave-level load/store
//     patterns identical to the previous 128-thr version.
//   - grid = 16 b x 256 l-tiles = 4096 blocks; a 16 KiB LDS ballast caps
//     residency at ~10 blocks/CU (< 16 needed for all-resident), so the
//     dispatcher streams blocks: later prologues (gather/sigmoid) overlap
//     earlier blocks' store phases instead of an all-chip prologue burst.
// Weights via wave-uniform s_loads (scalar cache); no barriers.
// ---------------------------------------------------------------------------
template <bool USE_XT>
__global__ __launch_bounds__(64) void deform_conv_kernel(
    const float* __restrict__ x,    // (B,1,L,C)
    const float* __restrict__ xT,   // (B,C,L) or nullptr
    const float* __restrict__ p_w, const float* __restrict__ p_b,
    const float* __restrict__ m_w, const float* __restrict__ m_b,
    const float* __restrict__ c_w, const float* __restrict__ c_b,
    float* __restrict__ out)        // (B,64,L,C)
{
    // Residency ballast: 16 KiB -> floor(160/16) = 10 blocks/CU.
    __shared__ float lds_ballast[4096];
    if ((int)threadIdx.x < 0) {  // never true; volatile keeps the alloc live
        *(volatile float*)&lds_ballast[0] = 1.f;
    }

    const int tid   = threadIdx.x;
    const int b     = blockIdx.x >> 8;   // 16 batches
    const int ltile = blockIdx.x & 255;  // 256 tiles of 16 positions
    const int l     = ltile * 16 + (tid >> 2);
    const int c0    = (tid & 3) * 4;     // channel quad

    const float* xb = x + (size_t)b * (LL * CC);

    // 3-tap conv inputs (zero pad at boundaries); coalesced float4 loads
    float s_m1[4] = {0.f, 0.f, 0.f, 0.f};
    float s_p1[4] = {0.f, 0.f, 0.f, 0.f};
    float s_0[4];
    {
        float4 v0 = *(const float4*)(xb + l * CC + c0);
        s_0[0] = v0.x; s_0[1] = v0.y; s_0[2] = v0.z; s_0[3] = v0.w;
        if (l > 0) {
            float4 vm = *(const float4*)(xb + (l - 1) * CC + c0);
            s_m1[0] = vm.x; s_m1[1] = vm.y; s_m1[2] = vm.z; s_m1[3] = vm.w;
        }
        if (l < LL - 1) {
            float4 vp = *(const float4*)(xb + (l + 1) * CC + c0);
            s_p1[0] = vp.x; s_p1[1] = vp.y; s_p1[2] = vp.z; s_p1[3] = vp.w;
        }
    }

    // x_off[c][k]: bilinear-gathered, masked samples.
    float xoff[4][KS];
    const float pl = (float)(l + 1);
    const float* xt0 = USE_XT ? (xT + (size_t)(b * CC + c0) * LL) : nullptr;
    #pragma unroll
    for (int k = 0; k < KS; ++k) {
        const float pw0 = p_w[k * 3 + 0], pw1 = p_w[k * 3 + 1],
                    pw2 = p_w[k * 3 + 2], pbk = p_b[k];
        const float mw0 = m_w[k * 3 + 0], mw1 = m_w[k * 3 + 1],
                    mw2 = m_w[k * 3 + 2], mbk = m_b[k];
        const float pn = (float)(k - 3);
        #pragma unroll
        for (int c = 0; c < 4; ++c) {
            float off  = pbk + pw0 * s_m1[c] + pw1 * s_0[c] + pw2 * s_p1[c];
            float mact = mbk + mw0 * s_m1[c] + mw1 * s_0[c] + mw2 * s_p1[c];
            float mm   = 1.f / (1.f + __expf(-mact));   // sigmoid

            float p    = pl + pn + off;
            float qltf = fminf(fmaxf(floorf(p), 0.f), (float)(LL - 1));
            float qrbf = fminf(qltf + 1.f, (float)(LL - 1));
            float pc   = fminf(fmaxf(p, 0.f), (float)(LL - 1));
            float glt  = 1.f + (qltf - pc);
            float grb  = 1.f - (qrbf - pc);

            float xlt, xrb;
            if (USE_XT) {
                // Contiguous along l: (xlt, xrb) is one dwordx2 load.
                // Load at min(ilt, LL-2); covers the ilt==LL-1 clamp case
                // (there q_lt==q_rb==LL-1 -> both samples are x[LL-1]).
                int iload = (int)fminf(qltf, (float)(LL - 2));
                const float* pr = xt0 + (size_t)c * LL + iload;
                float va = pr[0];
                float vb = pr[1];
                xlt = (qltf >= (float)(LL - 1)) ? vb : va;
                xrb = vb;
            } else {
                int ilt = (int)qltf;
                int irb = (int)qrbf;
                xlt = xb[ilt * CC + c0 + c];
                xrb = xb[irb * CC + c0 + c];
            }
            xoff[c][k] = (glt * xlt + grb * xrb) * mm;
        }
    }

    // 7 -> 64 output-channel dot. Weights via uniform (scalar) loads.
    float* outp = out + ((size_t)(b * OUTC) * LL + l) * CC + c0;
    #pragma unroll 4
    for (int o = 0; o < OUTC; ++o) {
        const float* cw = c_w + o * 7;   // uniform -> s_load
        const float w0 = cw[0], w1 = cw[1], w2 = cw[2], w3 = cw[3],
                    w4 = cw[4], w5 = cw[5], w6 = cw[6];
        const float bias = c_b[o];
        vfloat4 res;
        #pragma unroll
        for (int c = 0; c < 4; ++c) {
            float a = bias;
            a += w0 * xoff[c][0];
            a += w1 * xoff[c][1];
            a += w2 * xoff[c][2];
            a += w3 * xoff[c][3];
            a += w4 * xoff[c][4];
            a += w5 * xoff[c][5];
            a += w6 * xoff[c][6];
            res[c] = a;
        }
        *(vfloat4*)(outp + (size_t)o * (LL * CC)) = res;
    }
}

extern "C" void kernel_launch(void* const* d_in, const int* in_sizes, int n_in,
                              void* d_out, int out_size, void* d_ws, size_t ws_size,
                              hipStream_t stream) {
    const float* x   = (const float*)d_in[0];
    const float* p_w = (const float*)d_in[1];
    const float* p_b = (const float*)d_in[2];
    const float* m_w = (const float*)d_in[3];
    const float* m_b = (const float*)d_in[4];
    const float* c_w = (const float*)d_in[5];
    const float* c_b = (const float*)d_in[6];
    float* out = (float*)d_out;

    const size_t xt_bytes = (size_t)BB * CC * LL * sizeof(float);  // 4 MB
    if (d_ws != nullptr && ws_size >= xt_bytes) {
        float* xT = (float*)d_ws;
        transpose_kernel<<<dim3(BB * 64), dim3(256), 0, stream>>>(x, xT);
        deform_conv_kernel<true><<<dim3(BB * 256), dim3(64), 0, stream>>>(
            x, xT, p_w, p_b, m_w, m_b, c_w, c_b, out);
    } else {
        deform_conv_kernel<false><<<dim3(BB * 256), dim3(64), 0, stream>>>(
            x, nullptr, p_w, p_b, m_w, m_b, c_w, c_b, out);
    }
}